// Round 15
// baseline (174.712 us; speedup 1.0000x reference)
//
#include <hip/hip_runtime.h>
#include <hip/hip_bf16.h>
#include <math.h>

// ---------------------------------------------------------------------------
// HybridQuantumKernelNet forward, fp32 throughout.
// x[64,3,250,250] -> conv1(6,5x5,s2,p1)+relu -> [64,6,124,124]
//   -> maxpool2 s1 -> pool1 [64,123,123,6] (CHANNEL-LAST)
//   -> conv2(15,3x3,s2,p1)+relu -> [64,15,62,62] -> maxpool2 s1 -> [64,15,61,61]
//   -> flatten K=55815 -> fc1(120)+relu -> fc2(84)+relu -> fc3(1)
//   -> quantum head cos((z-p)/2)^4 @ kh_w + kh_b -> sigmoid -> [p,1-p]
//
// Ladder notes:
//  r6-r8: conv1 register-window spills at any VGPR cap -> LDS-stage.
//  r9-r14: conv1 LDS design stuck at ~38.5us across occupancy 3->6 blk/CU,
//      bank-swizzle, b128 reads -> NOT latency-bound; the global->LDS->reg
//      and conv->LDS->pool round-trips saturate the shared LDS unit.
//  r15 (this): conv1 rewritten ZERO-LDS: wave = 4 pooled rows x full width;
//      lane owns 2 conv cols; input halo via __shfl (7-float window);
//      vertical pool in-register (1.25x row redundancy); no barriers.
// ---------------------------------------------------------------------------

#define KTOT 55815            // 15*61*61
#define KTOT_PAD 55872        // A row stride (alignment only; tail guarded)
#define P1H 123               // pooled1 spatial
#define P2H 61                // pooled2 spatial
#define KC 64                 // fc1 K-chunk (per LDS stage)
#define KSPAN 128             // fc1 K per block (2 chunks)
#define NCHUNK 437            // ceil(55815/128)

// ---------------- Kernel 1: conv1 + relu + maxpool(2,s1), zero-LDS ---------
// Wave = one job: image b, pooled rows pb..pb+3 (conv rows pb..pb+4, input
// rows 2pb-1..2pb+9). Lane l: conv cols 2l,2l+1; loads x[4l..4l+3] per row
// (2 aligned f2); halo x[4l-1],x[4l+4],x[4l+5] via shfl. 60 FMA per
// (input-row, conv-row) pair; acc[5][6][2] in regs; pool fully in regs.
__global__ __launch_bounds__(256) void conv1_pool(
    const float* __restrict__ x, const float* __restrict__ w,
    const float* __restrict__ bias, float* __restrict__ out) {
  const int job = blockIdx.x * 4 + (threadIdx.x >> 6);   // 496*4 = 1984 exact
  const int l = threadIdx.x & 63;
  const int b = job / 31;
  const int pb = 4 * (job - b * 31);     // pooled row base: 0..120
  const float* xb = x + b * 187500;
  const int col0 = 4 * l;                // lane's private cols col0..col0+3

  float acc[5][6][2];
#pragma unroll
  for (int oc = 0; oc < 6; ++oc) {
    const float bv = bias[oc];
#pragma unroll
    for (int j = 0; j < 5; ++j) { acc[j][oc][0] = bv; acc[j][oc][1] = bv; }
  }

#pragma unroll
  for (int ic = 0; ic < 3; ++ic) {
    const float* xc = xb + ic * 62500;
#pragma unroll
    for (int ii = 0; ii < 11; ++ii) {    // input rows 2pb-1 .. 2pb+9
      const int iy = 2 * pb - 1 + ii;
      float r0 = 0.f, r1 = 0.f, r2 = 0.f, r3 = 0.f;
      if (iy >= 0 && iy <= 249) {        // iy<=249 guaranteed except guards
        const float* rp = xc + iy * 250;
        if (col0 <= 248) {
          const float2 v = *reinterpret_cast<const float2*>(rp + col0);
          r0 = v.x; r1 = v.y;
        }
        if (col0 <= 246) {
          const float2 v = *reinterpret_cast<const float2*>(rp + col0 + 2);
          r2 = v.x; r3 = v.y;
        }
      }
      float wnd[7];
      const float pm = __shfl(r3, l - 1);
      wnd[0] = (l == 0) ? 0.f : pm;      // left pad (ix = -1)
      wnd[1] = r0; wnd[2] = r1; wnd[3] = r2; wnd[4] = r3;
      wnd[5] = __shfl(r0, l + 1);
      wnd[6] = __shfl(r1, l + 1);
#pragma unroll
      for (int j = 0; j < 5; ++j) {
        const int ky = ii - 2 * j;
        if (ky < 0 || ky > 4) continue;  // compile-time pruned
#pragma unroll
        for (int oc = 0; oc < 6; ++oc) {
          const float* wp = w + oc * 75 + ic * 25 + ky * 5;
#pragma unroll
          for (int kx = 0; kx < 5; ++kx) {
            const float wv = wp[kx];     // wave-uniform s_load
            acc[j][oc][0] = fmaf(wnd[kx],     wv, acc[j][oc][0]);
            acc[j][oc][1] = fmaf(wnd[kx + 2], wv, acc[j][oc][1]);
          }
        }
      }
    }
  }

  // relu, then vertical pool in-place: acc[j] = max(acc[j], acc[j+1])
#pragma unroll
  for (int j = 0; j < 5; ++j)
#pragma unroll
    for (int oc = 0; oc < 6; ++oc) {
      acc[j][oc][0] = fmaxf(acc[j][oc][0], 0.f);
      acc[j][oc][1] = fmaxf(acc[j][oc][1], 0.f);
    }
#pragma unroll
  for (int j = 0; j < 4; ++j)
#pragma unroll
    for (int oc = 0; oc < 6; ++oc) {
      acc[j][oc][0] = fmaxf(acc[j][oc][0], acc[j + 1][oc][0]);
      acc[j][oc][1] = fmaxf(acc[j][oc][1], acc[j + 1][oc][1]);
    }

  // horizontal pool (needs conv col 2l+2 = neighbor's col 0) + store
#pragma unroll
  for (int j = 0; j < 4; ++j) {
    const int py = pb + j;
    float v0[6], v1[6];
#pragma unroll
    for (int oc = 0; oc < 6; ++oc) {
      const float nb = __shfl(acc[j][oc][0], l + 1);
      v0[oc] = fmaxf(acc[j][oc][0], acc[j][oc][1]);  // pooled col 2l
      v1[oc] = fmaxf(acc[j][oc][1], nb);             // pooled col 2l+1
    }
    if (py <= 122 && l <= 61) {
      float* ob = out + ((size_t)(b * P1H + py) * P1H + 2 * l) * 6;
      float2 t;
      t = {v0[0], v0[1]}; *reinterpret_cast<float2*>(ob + 0) = t;
      t = {v0[2], v0[3]}; *reinterpret_cast<float2*>(ob + 2) = t;
      t = {v0[4], v0[5]}; *reinterpret_cast<float2*>(ob + 4) = t;
      if (l < 61) {                       // pooled col 2l+1 <= 122
        t = {v1[0], v1[1]}; *reinterpret_cast<float2*>(ob + 6) = t;
        t = {v1[2], v1[3]}; *reinterpret_cast<float2*>(ob + 8) = t;
        t = {v1[4], v1[5]}; *reinterpret_cast<float2*>(ob + 10) = t;
      }
    }
  }
}

// ---------------- Kernel 2: conv2 + relu + maxpool(2,s1) fused -------------
__global__ __launch_bounds__(256, 2) void conv2_pool(
    const float* __restrict__ in, const float* __restrict__ w,
    const float* __restrict__ bias, float* __restrict__ A) {
  __shared__ float cs[15][16][16];
  const int b = blockIdx.y;
  const int ty = blockIdx.x / 5, tx = blockIdx.x % 5;
  const int py0 = ty * 15, px0 = tx * 15;
  const int tid = threadIdx.x;
  const int cyl = tid >> 4, cxl = tid & 15;
  const int cy = py0 + cyl, cx = px0 + cxl;
  const float* ib = in + (size_t)b * (P1H * P1H * 6);
  const bool cv = (cy < 62) && (cx < 62);
  const int iy0 = 2 * cy - 1, ix0 = 2 * cx - 1;

  float rin[54];                                  // layout [ky][kx][ic]
#pragma unroll
  for (int ky = 0; ky < 3; ++ky) {
    const int iy = iy0 + ky;
#pragma unroll
    for (int kx = 0; kx < 3; ++kx) {
      const int ix = ix0 + kx;
      const int e = (ky * 3 + kx) * 6;
      const bool ok = cv && (iy >= 0) && (iy < P1H) && (ix >= 0) && (ix < P1H);
      if (ok) {
        const float* p = ib + ((size_t)iy * P1H + ix) * 6;
        const float2 v0 = *reinterpret_cast<const float2*>(p + 0);
        const float2 v1 = *reinterpret_cast<const float2*>(p + 2);
        const float2 v2 = *reinterpret_cast<const float2*>(p + 4);
        rin[e + 0] = v0.x; rin[e + 1] = v0.y; rin[e + 2] = v1.x;
        rin[e + 3] = v1.y; rin[e + 4] = v2.x; rin[e + 5] = v2.y;
      } else {
        rin[e + 0] = 0.f; rin[e + 1] = 0.f; rin[e + 2] = 0.f;
        rin[e + 3] = 0.f; rin[e + 4] = 0.f; rin[e + 5] = 0.f;
      }
    }
  }
#pragma unroll
  for (int oc = 0; oc < 15; ++oc) {
    float a = bias[oc];
#pragma unroll
    for (int ic = 0; ic < 6; ++ic)
#pragma unroll
      for (int ky = 0; ky < 3; ++ky)
#pragma unroll
        for (int kx = 0; kx < 3; ++kx)
          a = fmaf(rin[(ky * 3 + kx) * 6 + ic],
                   w[oc * 54 + ic * 9 + ky * 3 + kx], a);
    cs[oc][cyl][cxl] = fmaxf(a, 0.f);
  }
  __syncthreads();
  if (tid < 225) {
    const int pyl = tid / 15, pxl = tid % 15;
    const int py = py0 + pyl, px = px0 + pxl;
    if (py < P2H && px < P2H) {
      float* ob = A + (size_t)b * KTOT_PAD;
#pragma unroll
      for (int oc = 0; oc < 15; ++oc) {
        const float v = fmaxf(fmaxf(cs[oc][pyl][pxl], cs[oc][pyl][pxl + 1]),
                              fmaxf(cs[oc][pyl + 1][pxl], cs[oc][pyl + 1][pxl + 1]));
        ob[oc * (P2H * P2H) + py * P2H + px] = v;
      }
    }
  }
}

// ---------------- Kernel 3: fc1 split-K partials, register-tiled -----------
// Block = K-span 128 as 2 sequential LDS chunks of KC=64 (r12 config).
__global__ __launch_bounds__(256) void fc1_partial(
    const float* __restrict__ A, const float* __restrict__ W,
    float* __restrict__ part) {
  __shared__ float As[64 * KC];                  // 16 KB
  __shared__ float Ws[120 * KC];                 // 30.7 KB
  const int tid = threadIdx.x;
  const int chunk = blockIdx.x;
  const int lane = tid & 63;
  const int wave = __builtin_amdgcn_readfirstlane(tid >> 6);
  const int mg = lane >> 3, ng = lane & 7;
  const int n0 = wave * 32;

  float acc[8][4];
#pragma unroll
  for (int r = 0; r < 8; ++r)
#pragma unroll
    for (int s = 0; s < 4; ++s) acc[r][s] = 0.0f;

  for (int half = 0; half < 2; ++half) {
    const int k0 = chunk * KSPAN + half * KC;
    const bool full = (k0 + KC <= KTOT);
    __syncthreads();                             // prev readers done

    for (int idx = tid; idx < 64 * 16; idx += 256) {
      const int m = idx >> 4, j = idx & 15;
      const int kg = k0 + 4 * j;
      float4 v;
      if (full || kg + 3 < KTOT) {
        v = *reinterpret_cast<const float4*>(A + (size_t)m * KTOT_PAD + kg);
      } else {
        v.x = (kg + 0 < KTOT) ? A[(size_t)m * KTOT_PAD + kg + 0] : 0.f;
        v.y = (kg + 1 < KTOT) ? A[(size_t)m * KTOT_PAD + kg + 1] : 0.f;
        v.z = (kg + 2 < KTOT) ? A[(size_t)m * KTOT_PAD + kg + 2] : 0.f;
        v.w = (kg + 3 < KTOT) ? A[(size_t)m * KTOT_PAD + kg + 3] : 0.f;
      }
      const int slot = (j & 8) | ((j & 7) ^ ((m >> 3) & 7));
      *reinterpret_cast<float4*>(&As[m * KC + 4 * slot]) = v;
    }
    if (full) {
      for (int idx = tid; idx < 120 * KC; idx += 256) {
        const int n = idx >> 6, k = idx & 63;
        const int j = k >> 2, q = k & 3;
        const int slot = (j & 8) | ((j & 7) ^ ((n >> 2) & 7));
        Ws[n * KC + 4 * slot + q] = W[(size_t)n * KTOT + k0 + k];
      }
    } else {
      for (int idx = tid; idx < 120 * KC; idx += 256) {
        const int n = idx >> 6, k = idx & 63;
        const int j = k >> 2, q = k & 3;
        const int slot = (j & 8) | ((j & 7) ^ ((n >> 2) & 7));
        const int kg = k0 + k;
        Ws[n * KC + 4 * slot + q] = (kg < KTOT) ? W[(size_t)n * KTOT + kg] : 0.f;
      }
    }
    __syncthreads();

    const float* Abase = As + mg * 8 * KC;
    const float* Wbase = Ws + (n0 + ng * 4) * KC;
#pragma unroll
    for (int k4 = 0; k4 < KC / 4; ++k4) {
      const int sA = 4 * ((k4 & 8) | ((k4 & 7) ^ mg));
      const int sW = 4 * ((k4 & 8) | ((k4 & 7) ^ ng));
      float4 a[8], wv[4];
#pragma unroll
      for (int r = 0; r < 8; ++r)
        a[r] = *reinterpret_cast<const float4*>(Abase + r * KC + sA);
#pragma unroll
      for (int s = 0; s < 4; ++s)
        wv[s] = *reinterpret_cast<const float4*>(Wbase + s * KC + sW);
#pragma unroll
      for (int r = 0; r < 8; ++r)
#pragma unroll
        for (int s = 0; s < 4; ++s) {
          float t = acc[r][s];
          t = fmaf(a[r].x, wv[s].x, t);
          t = fmaf(a[r].y, wv[s].y, t);
          t = fmaf(a[r].z, wv[s].z, t);
          t = fmaf(a[r].w, wv[s].w, t);
          acc[r][s] = t;
        }
    }
  }

  if (n0 + 4 * ng <= 116) {
    float* pb = part + (size_t)chunk * 7680 + n0 + 4 * ng;
#pragma unroll
    for (int r = 0; r < 8; ++r) {
      const float4 v = {acc[r][0], acc[r][1], acc[r][2], acc[r][3]};
      *reinterpret_cast<float4*>(pb + (mg * 8 + r) * 120) = v;
    }
  }
}

// ---------------- Kernel 4: reduce partials + bias + relu ------------------
__global__ __launch_bounds__(256) void fc1_reduce(
    const float* __restrict__ part, const float* __restrict__ bias,
    float* __restrict__ h1) {
  __shared__ float red[8][32];
  const int tid = threadIdx.x;
  const int q = tid >> 5, l = tid & 31;
  const int t = blockIdx.x * 32 + l;   // 240*32 = 7680
  float s = 0.0f;
  for (int c = q; c < NCHUNK; c += 8) s += part[(size_t)c * 7680 + t];
  red[q][l] = s;
  __syncthreads();
  if (q == 0) {
    float v = red[0][l] + red[1][l] + red[2][l] + red[3][l] +
              red[4][l] + red[5][l] + red[6][l] + red[7][l] + bias[t % 120];
    h1[t] = fmaxf(v, 0.0f);
  }
}

// ---------------- Kernel 5: fc2 + relu (21 blocks, 1 column/wave) ----------
__global__ __launch_bounds__(256) void fc2_kernel(
    const float* __restrict__ h1, const float* __restrict__ W,
    const float* __restrict__ bias, float* __restrict__ h2) {
  __shared__ float hs[64][121];
  const int tid = threadIdx.x;
  for (int i = tid; i < 7680; i += 256) hs[i / 120][i % 120] = h1[i];
  __syncthreads();
  const int m = tid & 63;
  const int j = blockIdx.x * 4 + __builtin_amdgcn_readfirstlane(tid >> 6);
  const float* wj = W + j * 120;
  float a = bias[j];
  for (int k = 0; k < 120; ++k) a = fmaf(hs[m][k], wj[k], a);
  h2[m * 84 + j] = fmaxf(a, 0.0f);
}

// ---------------- Kernel 6: fc3 + quantum kernel head + sigmoid ------------
__global__ void final_kernel(
    const float* __restrict__ h2, const float* __restrict__ w3,
    const float* __restrict__ b3, const float* __restrict__ proto,
    const float* __restrict__ khw, const float* __restrict__ khb,
    float* __restrict__ out) {
  const int m = threadIdx.x;  // 64 lanes
  const float* h = h2 + m * 84;
  float z = b3[0];
  for (int k = 0; k < 84; ++k) z = fmaf(h[k], w3[k], z);
  float logit = khb[0];
#pragma unroll
  for (int p = 0; p < 10; ++p) {
    const float c = cosf((z - proto[p]) * 0.5f);
    const float c2 = c * c;
    logit = fmaf(c2 * c2, khw[p], logit);
  }
  const float pr = 1.0f / (1.0f + expf(-logit));
  out[m * 2 + 0] = pr;
  out[m * 2 + 1] = 1.0f - pr;
}

// ---------------------------------------------------------------------------
extern "C" void kernel_launch(void* const* d_in, const int* in_sizes, int n_in,
                              void* d_out, int out_size, void* d_ws, size_t ws_size,
                              hipStream_t stream) {
  const float* x    = (const float*)d_in[0];
  const float* w1   = (const float*)d_in[1];
  const float* b1   = (const float*)d_in[2];
  const float* w2   = (const float*)d_in[3];
  const float* b2   = (const float*)d_in[4];
  const float* fw1  = (const float*)d_in[5];
  const float* fb1  = (const float*)d_in[6];
  const float* fw2  = (const float*)d_in[7];
  const float* fb2  = (const float*)d_in[8];
  const float* fw3  = (const float*)d_in[9];
  const float* fb3  = (const float*)d_in[10];
  const float* prot = (const float*)d_in[11];
  const float* khw  = (const float*)d_in[12];
  const float* khb  = (const float*)d_in[13];
  float* out = (float*)d_out;

  float* ws = (float*)d_ws;
  // pool1 (dead after conv2) is aliased by fc1 partials (written after).
  float* pool1 = ws;                           // 64*123*123*6 = 5,809,536 f
  float* part  = ws;                           // 437*7680     = 3,356,160 f (alias)
  float* A     = ws + 5809536;                 // 64*55872     = 3,575,808 f
  float* h1    = A + 3575808;                  // 7680 f
  float* h2    = h1 + 7680;                    // 5376 f

  conv1_pool <<<dim3(496), 256, 0, stream>>>(x, w1, b1, pool1);
  conv2_pool <<<dim3(25, 64), 256, 0, stream>>>(pool1, w2, b2, A);
  fc1_partial<<<dim3(NCHUNK), 256, 0, stream>>>(A, fw1, part);
  fc1_reduce <<<dim3(240), 256, 0, stream>>>(part, fb1, h1);
  fc2_kernel <<<dim3(21), 256, 0, stream>>>(h1, fw2, fb2, h2);
  final_kernel<<<dim3(1), 64, 0, stream>>>(h2, fw3, fb3, prot, khw, khb, out);
}